// Round 5
// baseline (9999.738 us; speedup 1.0000x reference)
//
#include <hip/hip_runtime.h>
#include <hip/hip_bf16.h>
#include <stdint.h>

typedef __hip_bfloat16 bf16;
typedef __attribute__((ext_vector_type(8))) unsigned short us8;

#define DEV __device__ __forceinline__

// ---- problem dims ----
static constexpr int Bn = 2, Ln = 2048, Hn = 2048, DINn = 4096, DSn = 128;
static constexpr int NHn = 64, FFn = 8192;
static constexpr int CONVD = DINn + 2 * DSn;            // 4352
static constexpr int DPROJ = 2 * DINn + 2 * DSn + NHn;  // 8512 = 133*64
static constexpr int BL = Bn * Ln;                      // 4096

DEV float bf2f(unsigned short x) {
  union { unsigned int u; float f; } v; v.u = ((unsigned int)x) << 16; return v.f;
}
DEV float bfload(const bf16* p) { return bf2f(*(const unsigned short*)p); }
DEV float sigmoidf_(float x) { return 1.f / (1.f + __expf(-x)); }

// ---------------- rmsnorm, fp32 in -> bf16 out (row = 2048) ----------------
__global__ __launch_bounds__(256) void rmsnorm_f32_k(
    const float* __restrict__ in, const float* __restrict__ g, bf16* __restrict__ out) {
  int row = blockIdx.x, tid = threadIdx.x;
  const float* rp = in + (size_t)row * Hn + tid * 8;
  float4 a = *(const float4*)rp;
  float4 b = *(const float4*)(rp + 4);
  float v[8] = {a.x, a.y, a.z, a.w, b.x, b.y, b.z, b.w};
  float ss = 0.f;
#pragma unroll
  for (int j = 0; j < 8; ++j) ss += v[j] * v[j];
#pragma unroll
  for (int o = 1; o < 64; o <<= 1) ss += __shfl_xor(ss, o, 64);
  __shared__ float red[4];
  if ((tid & 63) == 0) red[tid >> 6] = ss;
  __syncthreads();
  float sc = rsqrtf((red[0] + red[1] + red[2] + red[3]) / Hn + 1e-5f);
  float4 g0 = *(const float4*)(g + tid * 8);
  float4 g1 = *(const float4*)(g + tid * 8 + 4);
  float gv[8] = {g0.x, g0.y, g0.z, g0.w, g1.x, g1.y, g1.z, g1.w};
  us8 ov;
#pragma unroll
  for (int j = 0; j < 8; ++j)
    ((bf16*)&ov)[j] = __float2bfloat16(v[j] * sc * gv[j]);
  *(us8*)(out + (size_t)row * Hn + tid * 8) = ov;
}

// ---------------- GEMM: C[M][N] = A[M][K](bf16) @ W[K][N](fp32) ----------------
// 64x64 tile, BK=32, 256 threads, each thread 4x4 outputs.
// OutT = float or bf16. EPI 1: adds fp32 Res (same [M][N]).
template<int EPI, typename OutT>
__global__ __launch_bounds__(256) void ngemm_k(
    const bf16* __restrict__ A, const float* __restrict__ W,
    OutT* __restrict__ C, const float* __restrict__ Res,
    int K, int N) {
  __shared__ float As[64][33];
  __shared__ float Ws[32][68];
  int m0 = blockIdx.y * 64, n0 = blockIdx.x * 64;
  int tid = threadIdx.x;
  int tx = tid & 15, ty = tid >> 4;
  int ar = tid >> 2, ac = (tid & 3) * 8;   // A-stage: each thread 8 bf16 of row ar
  int wr = tid >> 3, wn = (tid & 7) * 8;   // W-stage: each thread 8 fp32 of k-row wr
  float acc[4][4] = {};
  for (int k0 = 0; k0 < K; k0 += 32) {
    us8 av = *(const us8*)(A + (size_t)(m0 + ar) * K + k0 + ac);
#pragma unroll
    for (int j = 0; j < 8; ++j) As[ar][ac + j] = bf2f(av[j]);
    const float* wp = W + (size_t)(k0 + wr) * N + n0 + wn;
    float4 w0 = *(const float4*)wp;
    float4 w1 = *(const float4*)(wp + 4);
    Ws[wr][wn + 0] = w0.x; Ws[wr][wn + 1] = w0.y;
    Ws[wr][wn + 2] = w0.z; Ws[wr][wn + 3] = w0.w;
    Ws[wr][wn + 4] = w1.x; Ws[wr][wn + 5] = w1.y;
    Ws[wr][wn + 6] = w1.z; Ws[wr][wn + 7] = w1.w;
    __syncthreads();
#pragma unroll
    for (int kk = 0; kk < 32; ++kk) {
      float a[4];
#pragma unroll
      for (int i = 0; i < 4; ++i) a[i] = As[ty * 4 + i][kk];
      float4 wv = *(const float4*)&Ws[kk][tx * 4];
#pragma unroll
      for (int i = 0; i < 4; ++i) {
        acc[i][0] = fmaf(a[i], wv.x, acc[i][0]);
        acc[i][1] = fmaf(a[i], wv.y, acc[i][1]);
        acc[i][2] = fmaf(a[i], wv.z, acc[i][2]);
        acc[i][3] = fmaf(a[i], wv.w, acc[i][3]);
      }
    }
    __syncthreads();
  }
#pragma unroll
  for (int i = 0; i < 4; ++i) {
    int row = m0 + ty * 4 + i;
#pragma unroll
    for (int j = 0; j < 4; ++j) {
      int col = n0 + tx * 4 + j;
      float v = acc[i][j];
      if (EPI == 1) v += Res[(size_t)row * N + col];
      if constexpr (__is_same(OutT, float)) C[(size_t)row * N + col] = v;
      else C[(size_t)row * N + col] = __float2bfloat16(v);
    }
  }
}

// ---------------- depthwise causal conv (DCONV=4) + bias + silu ----------------
// writes x part (c<DIN) as bf16, B/C part (c>=DIN) as fp32 [bt][256]
__global__ __launch_bounds__(256) void conv_silu_k(
    const bf16* __restrict__ proj, const float* __restrict__ cw,
    const float* __restrict__ cb, bf16* __restrict__ xb, float* __restrict__ bc) {
  int c = blockIdx.x * 256 + threadIdx.x;   // < CONVD
  int bt = blockIdx.y;
  int l = bt & (Ln - 1);
  const bf16* base = proj + (size_t)bt * DPROJ + DINn + c;
  float acc = cb[c];
#pragma unroll
  for (int k = 0; k < 4; ++k) {
    int dl = l - 3 + k;
    if (dl >= 0) acc += bfload(base + (ptrdiff_t)(k - 3) * DPROJ) * cw[c * 4 + k];
  }
  float r = acc * sigmoidf_(acc);
  if (c < DINn) xb[(size_t)bt * DINn + c] = __float2bfloat16(r);
  else          bc[(size_t)bt * 256 + (c - DINn)] = r;
}

// ---------------- dt = softplus(raw + bias), dA = exp(dt * -exp(A_log)) ----------------
__global__ __launch_bounds__(256) void dtda_k(
    const bf16* __restrict__ proj, const float* __restrict__ dt_bias,
    const float* __restrict__ A_log, float* __restrict__ dt, float* __restrict__ da) {
  int i = blockIdx.x * 256 + threadIdx.x;   // BL*NH
  int bt = i >> 6, h = i & 63;
  float raw = bfload(proj + (size_t)bt * DPROJ + (DINn + CONVD) + h) + dt_bias[h];
  float dtv = raw > 20.f ? raw : log1pf(expf(raw));
  float Ah = -expf(A_log[h]);
  dt[i] = dtv;
  da[i] = expf(dtv * Ah);
}

// ---------------- selective scan ----------------
// 256 blocks = (b, h, p-half). Thread (pl, sq): head-dim p = ph*32+pl, states [sq*16, sq*16+16).
// shfl-reduce over the 8 sq lanes; lane sq==0 writes y (bf16). No atomics.
__global__ __launch_bounds__(256) void scan_k(
    const bf16* __restrict__ xb, const float* __restrict__ bc,
    const float* __restrict__ dtb, const float* __restrict__ dab,
    const float* __restrict__ Dp, bf16* __restrict__ ys) {
  int idx = blockIdx.x;
  int b = idx >> 7, h = (idx >> 1) & 63, ph = idx & 1;
  int tid = threadIdx.x;
  int pl = tid >> 3, sq = tid & 7;
  int p = ph * 32 + pl;
  const bf16*  xp  = xb  + (size_t)b * Ln * DINn + h * 64 + p;
  const float* Bp  = bc  + (size_t)b * Ln * 256 + sq * 16;
  const float* Cp  = Bp + DSn;
  const float* dtp = dtb + (size_t)b * Ln * NHn + h;
  const float* dap = dab + (size_t)b * Ln * NHn + h;
  bf16* yp = ys + (size_t)b * Ln * DINn + h * 64 + p;
  float Dh = Dp[h];
  float st[16];
#pragma unroll
  for (int j = 0; j < 16; ++j) st[j] = 0.f;
  float4 B0 = *(const float4*)(Bp),     B1 = *(const float4*)(Bp + 4);
  float4 B2 = *(const float4*)(Bp + 8), B3 = *(const float4*)(Bp + 12);
  float4 C0 = *(const float4*)(Cp),     C1 = *(const float4*)(Cp + 4);
  float4 C2 = *(const float4*)(Cp + 8), C3 = *(const float4*)(Cp + 12);
  float xc = bfload(xp), dac = *dap, dtc = *dtp;
  for (int t = 0; t < Ln; ++t) {
    int tn = (t + 1 < Ln) ? t + 1 : t;
    const float* bb = Bp + (size_t)tn * 256;
    const float* cc = Cp + (size_t)tn * 256;
    float4 nB0 = *(const float4*)(bb),     nB1 = *(const float4*)(bb + 4);
    float4 nB2 = *(const float4*)(bb + 8), nB3 = *(const float4*)(bb + 12);
    float4 nC0 = *(const float4*)(cc),     nC1 = *(const float4*)(cc + 4);
    float4 nC2 = *(const float4*)(cc + 8), nC3 = *(const float4*)(cc + 12);
    float nx  = bfload(xp + (size_t)tn * DINn);
    float nda = dap[(size_t)tn * NHn];
    float ndt = dtp[(size_t)tn * NHn];

    float u = dtc * xc;
    float y0 = 0.f, y1 = 0.f, y2 = 0.f, y3 = 0.f;
#define SSTEP(i, acc, Bv, Cv) \
    st[i] = fmaf(st[i], dac, u * (Bv)); acc = fmaf(st[i], (Cv), acc);
    SSTEP(0,  y0, B0.x, C0.x)  SSTEP(1,  y1, B0.y, C0.y)
    SSTEP(2,  y2, B0.z, C0.z)  SSTEP(3,  y3, B0.w, C0.w)
    SSTEP(4,  y0, B1.x, C1.x)  SSTEP(5,  y1, B1.y, C1.y)
    SSTEP(6,  y2, B1.z, C1.z)  SSTEP(7,  y3, B1.w, C1.w)
    SSTEP(8,  y0, B2.x, C2.x)  SSTEP(9,  y1, B2.y, C2.y)
    SSTEP(10, y2, B2.z, C2.z)  SSTEP(11, y3, B2.w, C2.w)
    SSTEP(12, y0, B3.x, C3.x)  SSTEP(13, y1, B3.y, C3.y)
    SSTEP(14, y2, B3.z, C3.z)  SSTEP(15, y3, B3.w, C3.w)
#undef SSTEP
    float ysum = (y0 + y1) + (y2 + y3);
    ysum += __shfl_xor(ysum, 1, 64);
    ysum += __shfl_xor(ysum, 2, 64);
    ysum += __shfl_xor(ysum, 4, 64);
    if (sq == 0) yp[(size_t)t * DINn] = __float2bfloat16(fmaf(Dh, xc, ysum));
    B0 = nB0; B1 = nB1; B2 = nB2; B3 = nB3;
    C0 = nC0; C1 = nC1; C2 = nC2; C3 = nC3;
    xc = nx; dac = nda; dtc = ndt;
  }
}

// ---------------- gated rmsnorm: out = rmsnorm(y * silu(z)) * w  (row = 4096) ----------------
__global__ __launch_bounds__(256) void gated_norm_k(
    const bf16* __restrict__ ys, const bf16* __restrict__ proj,
    const float* __restrict__ gw, bf16* __restrict__ out) {
  int row = blockIdx.x, tid = threadIdx.x;
  const bf16* yr = ys + (size_t)row * DINn;
  const bf16* zr = proj + (size_t)row * DPROJ;
  float v[2][8];
  float ss = 0.f;
#pragma unroll
  for (int it = 0; it < 2; ++it) {
    int base = (it * 256 + tid) * 8;
    us8 y = *(const us8*)(yr + base);
    us8 z = *(const us8*)(zr + base);
#pragma unroll
    for (int j = 0; j < 8; ++j) {
      float zf = bf2f(z[j]);
      float val = bf2f(y[j]) * zf * sigmoidf_(zf);
      v[it][j] = val; ss += val * val;
    }
  }
#pragma unroll
  for (int o = 1; o < 64; o <<= 1) ss += __shfl_xor(ss, o, 64);
  __shared__ float red[4];
  if ((tid & 63) == 0) red[tid >> 6] = ss;
  __syncthreads();
  float sc = rsqrtf((red[0] + red[1] + red[2] + red[3]) / DINn + 1e-5f);
#pragma unroll
  for (int it = 0; it < 2; ++it) {
    int base = (it * 256 + tid) * 8;
    float4 g0 = *(const float4*)(gw + base);
    float4 g1 = *(const float4*)(gw + base + 4);
    float gv[8] = {g0.x, g0.y, g0.z, g0.w, g1.x, g1.y, g1.z, g1.w};
    us8 ov;
#pragma unroll
    for (int j = 0; j < 8; ++j)
      ((bf16*)&ov)[j] = __float2bfloat16(v[it][j] * sc * gv[j]);
    *(us8*)(out + (size_t)row * DINn + base) = ov;
  }
}

// ---------------- swiglu act: act = silu(gu[:, :FF]) * gu[:, FF:] ----------------
__global__ __launch_bounds__(256) void act_k(const bf16* __restrict__ gu, bf16* __restrict__ act) {
  int i = blockIdx.x * 256 + threadIdx.x;
  int row = i >> 10, g = i & 1023;
  const bf16* rp = gu + (size_t)row * (2 * FFn) + g * 8;
  us8 a = *(const us8*)(rp);
  us8 bx = *(const us8*)(rp + FFn);
  us8 ov;
#pragma unroll
  for (int j = 0; j < 8; ++j) {
    float av = bf2f(a[j]), bv = bf2f(bx[j]);
    ((bf16*)&ov)[j] = __float2bfloat16(av * sigmoidf_(av) * bv);
  }
  *(us8*)(act + (size_t)row * FFn + g * 8) = ov;
}

// ---------------- launch ----------------
extern "C" void kernel_launch(void* const* d_in, const int* in_sizes, int n_in,
                              void* d_out, int out_size, void* d_ws, size_t ws_size,
                              hipStream_t stream) {
  (void)in_sizes; (void)n_in; (void)out_size; (void)ws_size;
  const float* hidden  = (const float*)d_in[0];
  const float* w_in    = (const float*)d_in[1];
  const float* conv_w  = (const float*)d_in[2];
  const float* conv_b  = (const float*)d_in[3];
  const float* A_log   = (const float*)d_in[4];
  const float* D_ssm   = (const float*)d_in[5];
  const float* dt_bias = (const float*)d_in[6];
  const float* norm_w  = (const float*)d_in[7];
  const float* w_out   = (const float*)d_in[8];
  const float* ln1_w   = (const float*)d_in[9];
  const float* ln2_w   = (const float*)d_in[10];
  const float* w_gu    = (const float*)d_in[11];
  const float* w_dn    = (const float*)d_in[12];

  // ---- workspace layout, 201 MiB total, liveness-proven aliases ----
  char* ws = (char*)d_ws;
  const size_t OFF_PROJ = 0;                          // 69,730,304  proj bf16 [4096][8512]
  const size_t OFF_XB   = 69730304ull;                // 33,554,432  conv x bf16 [4096][4096]
  const size_t OFF_BC   = OFF_XB  + 33554432ull;      //  4,194,304  conv B/C fp32 [4096][256]
  const size_t OFF_DTB  = OFF_BC  + 4194304ull;       //  1,048,576
  const size_t OFF_DAB  = OFF_DTB + 1048576ull;       //  1,048,576
  const size_t OFF_YS   = OFF_DAB + 1048576ull;       // 33,554,432  scan out bf16 [4096][4096]
  const size_t OFF_YBF  = OFF_YS  + 33554432ull;      // 33,554,432  gated-norm out bf16
  const size_t OFF_HLN  = OFF_YBF + 33554432ull;      // 16,777,216  ln out bf16 [4096][2048]
  // aliases (all underlying regions dead at write time):
  const size_t OFF_GU   = 0;                          // 134,217,728 over proj..ys (dead after gated_norm)
  const size_t OFF_ACT  = 134217728ull;               // 67,108,864  over ys-tail/ybf/hln (dead after gu GEMM)

  bf16*  proj = (bf16*)(ws + OFF_PROJ);
  bf16*  xb   = (bf16*)(ws + OFF_XB);
  float* bc   = (float*)(ws + OFF_BC);
  float* dtb  = (float*)(ws + OFF_DTB);
  float* dab  = (float*)(ws + OFF_DAB);
  bf16*  ysb  = (bf16*)(ws + OFF_YS);
  bf16*  ybf  = (bf16*)(ws + OFF_YBF);
  bf16*  hln  = (bf16*)(ws + OFF_HLN);
  bf16*  gu   = (bf16*)(ws + OFF_GU);
  bf16*  act  = (bf16*)(ws + OFF_ACT);

  float* h_out = (float*)d_out;                 // output 0: h  (fp32)
  float* resid = h_out + (size_t)BL * Hn;       // output 1: residual (fp32)

  // ---- mixer ----
  rmsnorm_f32_k<<<BL, 256, 0, stream>>>(hidden, ln1_w, hln);
  ngemm_k<0, bf16><<<dim3(DPROJ / 64, BL / 64), 256, 0, stream>>>(hln, w_in, proj, nullptr, Hn, DPROJ);

  conv_silu_k<<<dim3(CONVD / 256, BL), 256, 0, stream>>>(proj, conv_w, conv_b, xb, bc);
  dtda_k<<<BL * NHn / 256, 256, 0, stream>>>(proj, dt_bias, A_log, dtb, dab);

  scan_k<<<256, 256, 0, stream>>>(xb, bc, dtb, dab, D_ssm, ysb);

  gated_norm_k<<<BL, 256, 0, stream>>>(ysb, proj, norm_w, ybf);
  ngemm_k<1, float><<<dim3(Hn / 64, BL / 64), 256, 0, stream>>>(ybf, w_out, resid, hidden, DINn, Hn);

  // ---- MLP ----
  rmsnorm_f32_k<<<BL, 256, 0, stream>>>(resid, ln2_w, hln);
  ngemm_k<0, bf16><<<dim3(2 * FFn / 64, BL / 64), 256, 0, stream>>>(hln, w_gu, gu, nullptr, Hn, 2 * FFn);
  act_k<<<BL * FFn / 8 / 256, 256, 0, stream>>>(gu, act);
  ngemm_k<0, float><<<dim3(Hn / 64, BL / 64), 256, 0, stream>>>(act, w_dn, h_out, nullptr, FFn, Hn);
}

// Round 6
// 2568.709 us; speedup vs baseline: 3.8929x; 3.8929x over previous
//
#include <hip/hip_runtime.h>
#include <hip/hip_bf16.h>
#include <stdint.h>

typedef __hip_bfloat16 bf16;
typedef __attribute__((ext_vector_type(8))) short bf16x8s;   // MFMA A/B fragment (8 bf16)
typedef __attribute__((ext_vector_type(4))) float f32x4;     // MFMA accumulator
typedef __attribute__((ext_vector_type(8))) unsigned short us8;

#define DEV __device__ __forceinline__

// ---- problem dims ----
static constexpr int Bn = 2, Ln = 2048, Hn = 2048, DINn = 4096, DSn = 128;
static constexpr int NHn = 64, FFn = 8192;
static constexpr int CONVD = DINn + 2 * DSn;            // 4352
static constexpr int DPROJ = 2 * DINn + 2 * DSn + NHn;  // 8512
static constexpr int DPROJP = 8576;                     // padded to 128 multiple (for GEMM grid)
static constexpr int BL = Bn * Ln;                      // 4096

DEV float bf2f(unsigned short x) {
  union { unsigned int u; float f; } v; v.u = ((unsigned int)x) << 16; return v.f;
}
DEV float bfload(const bf16* p) { return bf2f(*(const unsigned short*)p); }
DEV float sigmoidf_(float x) { return 1.f / (1.f + __expf(-x)); }

// ---------------- transpose fp32 [K][N] -> bf16 [N][K] ----------------
__global__ __launch_bounds__(256) void transpose_f2b_k(
    const float* __restrict__ in, bf16* __restrict__ out, int K, int N) {
  __shared__ bf16 t[32][33];
  int nb = blockIdx.x * 32, kb = blockIdx.y * 32;
  int tx = threadIdx.x & 31, ty = threadIdx.x >> 5;
#pragma unroll
  for (int r = 0; r < 32; r += 8)
    t[ty + r][tx] = __float2bfloat16(in[(size_t)(kb + ty + r) * N + nb + tx]);
  __syncthreads();
#pragma unroll
  for (int r = 0; r < 32; r += 8)
    out[(size_t)(nb + ty + r) * K + kb + tx] = t[tx][ty + r];
}

// ---------------- rmsnorm, fp32 in -> bf16 out (row = 2048) ----------------
__global__ __launch_bounds__(256) void rmsnorm_f32_k(
    const float* __restrict__ in, const float* __restrict__ g, bf16* __restrict__ out) {
  int row = blockIdx.x, tid = threadIdx.x;
  const float* rp = in + (size_t)row * Hn + tid * 8;
  float4 a = *(const float4*)rp;
  float4 b = *(const float4*)(rp + 4);
  float v[8] = {a.x, a.y, a.z, a.w, b.x, b.y, b.z, b.w};
  float ss = 0.f;
#pragma unroll
  for (int j = 0; j < 8; ++j) ss += v[j] * v[j];
#pragma unroll
  for (int o = 1; o < 64; o <<= 1) ss += __shfl_xor(ss, o, 64);
  __shared__ float red[4];
  if ((tid & 63) == 0) red[tid >> 6] = ss;
  __syncthreads();
  float sc = rsqrtf((red[0] + red[1] + red[2] + red[3]) / Hn + 1e-5f);
  float4 g0 = *(const float4*)(g + tid * 8);
  float4 g1 = *(const float4*)(g + tid * 8 + 4);
  float gv[8] = {g0.x, g0.y, g0.z, g0.w, g1.x, g1.y, g1.z, g1.w};
  us8 ov;
#pragma unroll
  for (int j = 0; j < 8; ++j)
    ((bf16*)&ov)[j] = __float2bfloat16(v[j] * sc * gv[j]);
  *(us8*)(out + (size_t)row * Hn + tid * 8) = ov;
}

// ---------------- MFMA GEMM: C[M][N] = A[M][lda] (bf16) @ Bt[Np][K]^T (bf16) ----------------
// 128x128 tile, BK=64, 4 waves (2x2), 16x16x32 bf16 MFMA, global_load_lds staging.
// OutT: float or bf16. EPI 1: adds fp32 Res[M][N]. Stores guarded by col<N.
template<int EPI, typename OutT>
__global__ __launch_bounds__(256) void gemm_k(
    const bf16* __restrict__ A, const bf16* __restrict__ Bt,
    OutT* __restrict__ C, const float* __restrict__ Res,
    int K, int lda, int N) {
  __shared__ bf16 As[128 * 64];
  __shared__ bf16 Bs[128 * 64];
  int m0 = blockIdx.y * 128, n0 = blockIdx.x * 128;
  int tid = threadIdx.x;
  int lane = tid & 63;
  int wid = tid >> 6;
  int wr = wid >> 1, wc = wid & 1;
  f32x4 acc[4][4] = {};
  int srow = tid >> 3;
  int scol = (tid & 7) * 8;
  const bf16* Ag = A + (size_t)(m0 + srow) * lda + scol;
  const bf16* Bg = Bt + (size_t)(n0 + srow) * K + scol;
  char* AsB = (char*)As;
  char* BsB = (char*)Bs;
  for (int k0 = 0; k0 < K; k0 += 64) {
#pragma unroll
    for (int i = 0; i < 4; ++i)
      __builtin_amdgcn_global_load_lds(
          (const __attribute__((address_space(1))) unsigned int*)(Ag + (size_t)i * 32 * lda + k0),
          (__attribute__((address_space(3))) unsigned int*)(AsB + i * 4096 + tid * 16),
          16, 0, 0);
#pragma unroll
    for (int i = 0; i < 4; ++i)
      __builtin_amdgcn_global_load_lds(
          (const __attribute__((address_space(1))) unsigned int*)(Bg + (size_t)i * 32 * K + k0),
          (__attribute__((address_space(3))) unsigned int*)(BsB + i * 4096 + tid * 16),
          16, 0, 0);
    __syncthreads();
#pragma unroll
    for (int kk = 0; kk < 2; ++kk) {
      int krow = kk * 32 + (lane >> 4) * 8;
      bf16x8s af[4], bfv[4];
#pragma unroll
      for (int m = 0; m < 4; ++m)
        af[m] = *(const bf16x8s*)(As + (wr * 64 + m * 16 + (lane & 15)) * 64 + krow);
#pragma unroll
      for (int n = 0; n < 4; ++n)
        bfv[n] = *(const bf16x8s*)(Bs + (wc * 64 + n * 16 + (lane & 15)) * 64 + krow);
#pragma unroll
      for (int m = 0; m < 4; ++m)
#pragma unroll
        for (int n = 0; n < 4; ++n)
          acc[m][n] = __builtin_amdgcn_mfma_f32_16x16x32_bf16(af[m], bfv[n], acc[m][n], 0, 0, 0);
    }
    __syncthreads();
  }
#pragma unroll
  for (int m = 0; m < 4; ++m) {
#pragma unroll
    for (int n = 0; n < 4; ++n) {
      int col = n0 + wc * 64 + n * 16 + (lane & 15);
      if (col < N) {
#pragma unroll
        for (int r = 0; r < 4; ++r) {
          int row = m0 + wr * 64 + m * 16 + (lane >> 4) * 4 + r;
          float vv = acc[m][n][r];
          if (EPI == 1) vv += Res[(size_t)row * N + col];
          if constexpr (__is_same(OutT, float)) C[(size_t)row * N + col] = vv;
          else C[(size_t)row * N + col] = __float2bfloat16(vv);
        }
      }
    }
  }
}

// ---------------- depthwise causal conv (DCONV=4) + bias + silu ----------------
// writes x part (c<DIN) as bf16, B/C part (c>=DIN) as fp32 [bt][256]
__global__ __launch_bounds__(256) void conv_silu_k(
    const bf16* __restrict__ proj, const float* __restrict__ cw,
    const float* __restrict__ cb, bf16* __restrict__ xb, float* __restrict__ bc) {
  int c = blockIdx.x * 256 + threadIdx.x;   // < CONVD
  int bt = blockIdx.y;
  int l = bt & (Ln - 1);
  const bf16* base = proj + (size_t)bt * DPROJ + DINn + c;
  float acc = cb[c];
#pragma unroll
  for (int k = 0; k < 4; ++k) {
    int dl = l - 3 + k;
    if (dl >= 0) acc += bfload(base + (ptrdiff_t)(k - 3) * DPROJ) * cw[c * 4 + k];
  }
  float r = acc * sigmoidf_(acc);
  if (c < DINn) xb[(size_t)bt * DINn + c] = __float2bfloat16(r);
  else          bc[(size_t)bt * 256 + (c - DINn)] = r;
}

// ---------------- dt = softplus(raw + bias), dA = exp(dt * -exp(A_log)) ----------------
__global__ __launch_bounds__(256) void dtda_k(
    const bf16* __restrict__ proj, const float* __restrict__ dt_bias,
    const float* __restrict__ A_log, float* __restrict__ dt, float* __restrict__ da) {
  int i = blockIdx.x * 256 + threadIdx.x;   // BL*NH
  int bt = i >> 6, h = i & 63;
  float raw = bfload(proj + (size_t)bt * DPROJ + (DINn + CONVD) + h) + dt_bias[h];
  float dtv = raw > 20.f ? raw : log1pf(expf(raw));
  float Ah = -expf(A_log[h]);
  dt[i] = dtv;
  da[i] = expf(dtv * Ah);
}

// ---------------- selective scan ----------------
// 256 blocks = (b, h, p-half). Thread (pl, sq): head-dim p = ph*32+pl, states [sq*16, sq*16+16).
// shfl-reduce over the 8 sq lanes; lane sq==0 writes y (bf16). No atomics.
__global__ __launch_bounds__(256) void scan_k(
    const bf16* __restrict__ xb, const float* __restrict__ bc,
    const float* __restrict__ dtb, const float* __restrict__ dab,
    const float* __restrict__ Dp, bf16* __restrict__ ys) {
  int idx = blockIdx.x;
  int b = idx >> 7, h = (idx >> 1) & 63, ph = idx & 1;
  int tid = threadIdx.x;
  int pl = tid >> 3, sq = tid & 7;
  int p = ph * 32 + pl;
  const bf16*  xp  = xb  + (size_t)b * Ln * DINn + h * 64 + p;
  const float* Bp  = bc  + (size_t)b * Ln * 256 + sq * 16;
  const float* Cp  = Bp + DSn;
  const float* dtp = dtb + (size_t)b * Ln * NHn + h;
  const float* dap = dab + (size_t)b * Ln * NHn + h;
  bf16* yp = ys + (size_t)b * Ln * DINn + h * 64 + p;
  float Dh = Dp[h];
  float st[16];
#pragma unroll
  for (int j = 0; j < 16; ++j) st[j] = 0.f;
  float4 B0 = *(const float4*)(Bp),     B1 = *(const float4*)(Bp + 4);
  float4 B2 = *(const float4*)(Bp + 8), B3 = *(const float4*)(Bp + 12);
  float4 C0 = *(const float4*)(Cp),     C1 = *(const float4*)(Cp + 4);
  float4 C2 = *(const float4*)(Cp + 8), C3 = *(const float4*)(Cp + 12);
  float xc = bfload(xp), dac = *dap, dtc = *dtp;
  for (int t = 0; t < Ln; ++t) {
    int tn = (t + 1 < Ln) ? t + 1 : t;
    const float* bb = Bp + (size_t)tn * 256;
    const float* cc = Cp + (size_t)tn * 256;
    float4 nB0 = *(const float4*)(bb),     nB1 = *(const float4*)(bb + 4);
    float4 nB2 = *(const float4*)(bb + 8), nB3 = *(const float4*)(bb + 12);
    float4 nC0 = *(const float4*)(cc),     nC1 = *(const float4*)(cc + 4);
    float4 nC2 = *(const float4*)(cc + 8), nC3 = *(const float4*)(cc + 12);
    float nx  = bfload(xp + (size_t)tn * DINn);
    float nda = dap[(size_t)tn * NHn];
    float ndt = dtp[(size_t)tn * NHn];

    float u = dtc * xc;
    float y0 = 0.f, y1 = 0.f, y2 = 0.f, y3 = 0.f;
#define SSTEP(i, acc, Bv, Cv) \
    st[i] = fmaf(st[i], dac, u * (Bv)); acc = fmaf(st[i], (Cv), acc);
    SSTEP(0,  y0, B0.x, C0.x)  SSTEP(1,  y1, B0.y, C0.y)
    SSTEP(2,  y2, B0.z, C0.z)  SSTEP(3,  y3, B0.w, C0.w)
    SSTEP(4,  y0, B1.x, C1.x)  SSTEP(5,  y1, B1.y, C1.y)
    SSTEP(6,  y2, B1.z, C1.z)  SSTEP(7,  y3, B1.w, C1.w)
    SSTEP(8,  y0, B2.x, C2.x)  SSTEP(9,  y1, B2.y, C2.y)
    SSTEP(10, y2, B2.z, C2.z)  SSTEP(11, y3, B2.w, C2.w)
    SSTEP(12, y0, B3.x, C3.x)  SSTEP(13, y1, B3.y, C3.y)
    SSTEP(14, y2, B3.z, C3.z)  SSTEP(15, y3, B3.w, C3.w)
#undef SSTEP
    float ysum = (y0 + y1) + (y2 + y3);
    ysum += __shfl_xor(ysum, 1, 64);
    ysum += __shfl_xor(ysum, 2, 64);
    ysum += __shfl_xor(ysum, 4, 64);
    if (sq == 0) yp[(size_t)t * DINn] = __float2bfloat16(fmaf(Dh, xc, ysum));
    B0 = nB0; B1 = nB1; B2 = nB2; B3 = nB3;
    C0 = nC0; C1 = nC1; C2 = nC2; C3 = nC3;
    xc = nx; dac = nda; dtc = ndt;
  }
}

// ---------------- gated rmsnorm: out = rmsnorm(y * silu(z)) * w  (row = 4096) ----------------
__global__ __launch_bounds__(256) void gated_norm_k(
    const bf16* __restrict__ ys, const bf16* __restrict__ proj,
    const float* __restrict__ gw, bf16* __restrict__ out) {
  int row = blockIdx.x, tid = threadIdx.x;
  const bf16* yr = ys + (size_t)row * DINn;
  const bf16* zr = proj + (size_t)row * DPROJ;
  float v[2][8];
  float ss = 0.f;
#pragma unroll
  for (int it = 0; it < 2; ++it) {
    int base = (it * 256 + tid) * 8;
    us8 y = *(const us8*)(yr + base);
    us8 z = *(const us8*)(zr + base);
#pragma unroll
    for (int j = 0; j < 8; ++j) {
      float zf = bf2f(z[j]);
      float val = bf2f(y[j]) * zf * sigmoidf_(zf);
      v[it][j] = val; ss += val * val;
    }
  }
#pragma unroll
  for (int o = 1; o < 64; o <<= 1) ss += __shfl_xor(ss, o, 64);
  __shared__ float red[4];
  if ((tid & 63) == 0) red[tid >> 6] = ss;
  __syncthreads();
  float sc = rsqrtf((red[0] + red[1] + red[2] + red[3]) / DINn + 1e-5f);
#pragma unroll
  for (int it = 0; it < 2; ++it) {
    int base = (it * 256 + tid) * 8;
    float4 g0 = *(const float4*)(gw + base);
    float4 g1 = *(const float4*)(gw + base + 4);
    float gv[8] = {g0.x, g0.y, g0.z, g0.w, g1.x, g1.y, g1.z, g1.w};
    us8 ov;
#pragma unroll
    for (int j = 0; j < 8; ++j)
      ((bf16*)&ov)[j] = __float2bfloat16(v[it][j] * sc * gv[j]);
    *(us8*)(out + (size_t)row * DINn + base) = ov;
  }
}

// ---------------- swiglu act, IN-PLACE on gu: gu[row][f] = silu(gu[row][f]) * gu[row][FF+f] ----------------
__global__ __launch_bounds__(256) void act_k(bf16* __restrict__ gu) {
  int i = blockIdx.x * 256 + threadIdx.x;
  int row = i >> 10, g = i & 1023;
  bf16* rp = gu + (size_t)row * (2 * FFn) + g * 8;
  us8 a = *(const us8*)(rp);
  us8 bx = *(const us8*)(rp + FFn);
  us8 ov;
#pragma unroll
  for (int j = 0; j < 8; ++j) {
    float av = bf2f(a[j]), bv = bf2f(bx[j]);
    ((bf16*)&ov)[j] = __float2bfloat16(av * sigmoidf_(av) * bv);
  }
  *(us8*)rp = ov;
}

// ---------------- launch ----------------
extern "C" void kernel_launch(void* const* d_in, const int* in_sizes, int n_in,
                              void* d_out, int out_size, void* d_ws, size_t ws_size,
                              hipStream_t stream) {
  (void)in_sizes; (void)n_in; (void)out_size; (void)ws_size;
  const float* hidden  = (const float*)d_in[0];
  const float* w_in    = (const float*)d_in[1];
  const float* conv_w  = (const float*)d_in[2];
  const float* conv_b  = (const float*)d_in[3];
  const float* A_log   = (const float*)d_in[4];
  const float* D_ssm   = (const float*)d_in[5];
  const float* dt_bias = (const float*)d_in[6];
  const float* norm_w  = (const float*)d_in[7];
  const float* w_out   = (const float*)d_in[8];
  const float* ln1_w   = (const float*)d_in[9];
  const float* ln2_w   = (const float*)d_in[10];
  const float* w_gu    = (const float*)d_in[11];
  const float* w_dn    = (const float*)d_in[12];

  // ---- workspace layout, 260.6 MiB peak, liveness-checked ----
  char* ws = (char*)d_ws;
  const size_t OFF_WT   = 0;                          // 67,108,864  weight-T buffer (max: w_guT)
  const size_t OFF_PROJ = 67108864ull;                // 69,730,304  proj bf16 [4096][8512]
  const size_t OFF_XB   = OFF_PROJ + 69730304ull;     // 33,554,432  conv x bf16 [4096][4096]
  const size_t OFF_BC   = OFF_XB  + 33554432ull;      //  4,194,304  conv B/C fp32 [4096][256]
  const size_t OFF_DTB  = OFF_BC  + 4194304ull;       //  1,048,576
  const size_t OFF_DAB  = OFF_DTB + 1048576ull;       //  1,048,576
  const size_t OFF_YS   = OFF_DAB + 1048576ull;       // 33,554,432  scan out bf16 [4096][4096]
  const size_t OFF_YBF  = OFF_YS  + 33554432ull;      // 33,554,432  gated-norm out bf16
  const size_t OFF_HLN  = OFF_YBF + 33554432ull;      // 16,777,216  ln out bf16 [4096][2048]
  // alias: gu bf16 [4096][16384] over proj..ys-head (all dead after gated_norm; excludes wT/ybf/hln)
  const size_t OFF_GU   = OFF_PROJ;                   // 134,217,728 -> ends at 201,326,592

  bf16*  wT   = (bf16*)(ws + OFF_WT);
  bf16*  proj = (bf16*)(ws + OFF_PROJ);
  bf16*  xb   = (bf16*)(ws + OFF_XB);
  float* bc   = (float*)(ws + OFF_BC);
  float* dtb  = (float*)(ws + OFF_DTB);
  float* dab  = (float*)(ws + OFF_DAB);
  bf16*  ysb  = (bf16*)(ws + OFF_YS);
  bf16*  ybf  = (bf16*)(ws + OFF_YBF);
  bf16*  hln  = (bf16*)(ws + OFF_HLN);
  bf16*  gu   = (bf16*)(ws + OFF_GU);

  float* h_out = (float*)d_out;                 // output 0: h  (fp32)
  float* resid = h_out + (size_t)BL * Hn;       // output 1: residual (fp32)

  // ---- mixer ----
  transpose_f2b_k<<<dim3(DPROJ / 32, Hn / 32), 256, 0, stream>>>(w_in, wT, Hn, DPROJ);
  hipMemsetAsync(wT + (size_t)DPROJ * Hn, 0, (size_t)(DPROJP - DPROJ) * Hn * 2, stream);
  rmsnorm_f32_k<<<BL, 256, 0, stream>>>(hidden, ln1_w, hln);
  gemm_k<0, bf16><<<dim3(DPROJP / 128, BL / 128), 256, 0, stream>>>(
      hln, wT, proj, nullptr, Hn, Hn, DPROJ);

  conv_silu_k<<<dim3(CONVD / 256, BL), 256, 0, stream>>>(proj, conv_w, conv_b, xb, bc);
  dtda_k<<<BL * NHn / 256, 256, 0, stream>>>(proj, dt_bias, A_log, dtb, dab);

  scan_k<<<256, 256, 0, stream>>>(xb, bc, dtb, dab, D_ssm, ysb);

  gated_norm_k<<<BL, 256, 0, stream>>>(ysb, proj, norm_w, ybf);
  transpose_f2b_k<<<dim3(Hn / 32, DINn / 32), 256, 0, stream>>>(w_out, wT, DINn, Hn);
  gemm_k<1, float><<<dim3(Hn / 128, BL / 128), 256, 0, stream>>>(
      ybf, wT, resid, hidden, DINn, DINn, Hn);

  // ---- MLP ----
  rmsnorm_f32_k<<<BL, 256, 0, stream>>>(resid, ln2_w, hln);
  transpose_f2b_k<<<dim3(2 * FFn / 32, Hn / 32), 256, 0, stream>>>(w_gu, wT, Hn, 2 * FFn);
  gemm_k<0, bf16><<<dim3(2 * FFn / 128, BL / 128), 256, 0, stream>>>(
      hln, wT, gu, nullptr, Hn, Hn, 2 * FFn);
  act_k<<<BL * FFn / 8 / 256, 256, 0, stream>>>(gu);
  transpose_f2b_k<<<dim3(Hn / 32, FFn / 32), 256, 0, stream>>>(w_dn, wT, FFn, Hn);
  gemm_k<0, float><<<dim3(Hn / 128, BL / 128), 256, 0, stream>>>(
      gu, wT, h_out, nullptr, FFn, 2 * FFn, Hn);
}